// Round 8
// baseline (666.281 us; speedup 1.0000x reference)
//
#include <hip/hip_runtime.h>

// ---------------------------------------------------------------------------
// RGCN (basis decomposition), 2 layers. N=50000, E=1e6, H=128, O=64, R=16.
// Round 17: model fitted to r10-r16: barrier-paced CONVOY. 3 blocks/CU stay
// phase-aligned; each ~5900cy phase = serialized bursts, dominated by the
// per-CU LDS pipe: 12 waves x ~210cy = 2520cy, because all 4 waves of a
// block read the SAME xs (8KB) + pmat (4x read redundancy; columns split
// 4 ways). r16's small win (-3.5%) matches removing 12% of the LDS burst.
// Change: 2-WAVE BLOCKS (128 threads). Each wave owns OUT/2 columns
// (NT=4 for OUT=128, NT=2 for OUT=64) -> xs/pmat read redundancy 4x -> 2x;
// per-CU LDS+VALU+issue demand per edge ~halves. W stays register-resident
// (wf 16 frags). Staging: 4 rows/thread (r0=t>>4 in [0,8), rows r0+{0,8,
// 16,24}). Gathers now IN-PHASE (issue early / ds_write late; convoy slack
// covers the ~900cy) -> G pipeline regs dropped. Entries stay depth-1
// ping/pong (qE*/pE*); hentry in-phase. launch_bounds(128,2) (VGPR cap 256,
// no spill: WRITE_SIZE must stay 12.5MB).
// Kept: eps-permutation ys-free agg (r15/r16, verified), pmat handler
// scatter+clear (isHandler=(t&3)==0, myCol=t>>2), barrier_nodrain, setprio,
// descriptor list, preprocessing. MFMA layouts identical to r16 (passing).
// ---------------------------------------------------------------------------

typedef short bf16x8 __attribute__((ext_vector_type(8)));
typedef float f32x4 __attribute__((ext_vector_type(4)));

#define RELS 16
#define HDIM 128
#define DSTBLK 66
#define MT_P 5    // ceil(66/16): pmat has 80 rows
#define CHUNK 32
#define MAXBINS 12288
#define MAXCH 96  // chunks/block: mean ~49; needs edges>2592 (35 sigma) to overflow

__device__ inline unsigned short f2bf(float f) {
  unsigned int u = __float_as_uint(f);
  unsigned int r = u + 0x7FFFu + ((u >> 16) & 1u);
  return (unsigned short)(r >> 16);
}

// packed bf16 pair via HW cvt (RNE); no builtin on gfx950 -> inline asm
__device__ inline unsigned cvtpk(float lo, float hi) {
  unsigned r;
  asm("v_cvt_pk_bf16_f32 %0, %1, %2" : "=v"(r) : "v"(lo), "v"(hi));
  return r;
}

// Workgroup barrier WITHOUT the vmcnt(0) drain __syncthreads() emits.
// Correct here because inter-wave communication is exclusively through LDS:
// lgkmcnt(0) makes all DS writes visible; in-flight global loads only feed
// this wave's registers (compiler inserts counted vmcnt at first use).
__device__ inline void barrier_nodrain() {
  __builtin_amdgcn_sched_barrier(0);
  asm volatile("s_waitcnt lgkmcnt(0)" ::: "memory");
  __builtin_amdgcn_s_barrier();
  __builtin_amdgcn_sched_barrier(0);
}

__global__ void cvt_bf16(const float* __restrict__ in, unsigned short* __restrict__ out, int n8) {
  int i = blockIdx.x * blockDim.x + threadIdx.x;
  if (i >= n8) return;
  float4 a = ((const float4*)in)[i * 2];
  float4 b = ((const float4*)in)[i * 2 + 1];
  uint4 o;
  o.x = (unsigned)f2bf(a.x) | ((unsigned)f2bf(a.y) << 16);
  o.y = (unsigned)f2bf(a.z) | ((unsigned)f2bf(a.w) << 16);
  o.z = (unsigned)f2bf(b.x) | ((unsigned)f2bf(b.y) << 16);
  o.w = (unsigned)f2bf(b.z) | ((unsigned)f2bf(b.w) << 16);
  ((uint4*)out)[i] = o;
}

// Wt[r][o][k] (bf16, transposed) = sum_b comp[r,b] * V[b,k,o]
__global__ void compute_w(const float* __restrict__ comp, const float* __restrict__ V,
                          unsigned short* __restrict__ Wt, int IO) {
  int idx = blockIdx.x * blockDim.x + threadIdx.x;
  if (idx >= RELS * IO * HDIM) return;
  int k = idx & (HDIM - 1);
  int o = (idx >> 7) % IO;
  int r = idx / (IO * HDIM);
  float s = 0.f;
#pragma unroll
  for (int b = 0; b < RELS; b++)
    s = fmaf(comp[r * RELS + b], V[(size_t)b * HDIM * IO + (size_t)k * IO + o], s);
  Wt[idx] = f2bf(s);
}

__global__ void hist_bins(const int* __restrict__ dst, const int* __restrict__ etype,
                          int n, int nbins, int* __restrict__ counts) {
  __shared__ int lh[MAXBINS];
  for (int j = threadIdx.x; j < nbins; j += blockDim.x) lh[j] = 0;
  __syncthreads();
  for (int i = blockIdx.x * blockDim.x + threadIdx.x; i < n; i += gridDim.x * blockDim.x)
    atomicAdd(&lh[(dst[i] / DSTBLK) * RELS + etype[i]], 1);
  __syncthreads();
  for (int j = threadIdx.x; j < nbins; j += blockDim.x) {
    int c = lh[j];
    if (c) atomicAdd(&counts[j], c);
  }
}

// exclusive scan of counts padded to multiples of 16 (parallel prefix)
__global__ void scan_offsets(const int* __restrict__ counts, int* __restrict__ offsets, int nbins) {
  __shared__ int csum[256];
  const int t = threadIdx.x;
  const int CH = (nbins + 255) / 256;
  int lo = t * CH, hi = min(lo + CH, nbins);
  int s = 0;
  for (int i = lo; i < hi; i++) s += (counts[i] + 15) & ~15;
  csum[t] = s;
  __syncthreads();
#pragma unroll
  for (int d = 1; d < 256; d <<= 1) {  // Hillis-Steele inclusive scan
    int v = (t >= d) ? csum[t - d] : 0;
    __syncthreads();
    csum[t] += v;
    __syncthreads();
  }
  int run = (t == 0) ? 0 : csum[t - 1];
  for (int i = lo; i < hi; i++) {
    offsets[i] = run;
    run += (counts[i] + 15) & ~15;
  }
  if (lo < nbins && hi == nbins) offsets[nbins] = run;
}

// ebuf[p] = {src | dloc<<20, norm_f32_bits}; dloc = d % DSTBLK (7 bits).
// Pad slots unwritten; all consumers guard by real counts.
__global__ void scatter_bins(const int* __restrict__ src, const int* __restrict__ dst,
                             const int* __restrict__ etype, const float* __restrict__ norm,
                             int n, const int* __restrict__ offsets, int* __restrict__ cursor,
                             uint2* __restrict__ ebuf) {
  for (int i = blockIdx.x * blockDim.x + threadIdx.x; i < n; i += gridDim.x * blockDim.x) {
    int d = dst[i];
    int blk = d / DSTBLK;
    int b = blk * RELS + etype[i];
    int p = offsets[b] + atomicAdd(&cursor[b], 1);
    ebuf[p] = make_uint2((unsigned)src[i] | ((unsigned)(d - blk * DSTBLK) << 20),
                         __float_as_uint(norm[i]));
  }
}

// One phase (parity CB literal): (1) entries(ci+2) -> oE*, (2) gathers(ci+1)
// from iE* (1-phase-old), (3) hentry(ci+1) in-phase, (4) GEMM1 on xs[CB] ->
// dacc regs, (5) lane-local cvt_pk pack + agg pacc += pmat[CB] @ B,
// (6) write xs[CB^1]/pmat[CB^1] for ci+1, (7) barrier_nodrain.
#define PHASE(CB, iE0, iE1, iE2, iE3, oE0, oE1, oE2, oE3, PDW)                  \
  {                                                                             \
    int2 dc = descS[ci];                                                        \
    const int nRows = dc.y & 0xFF;                                              \
    const int rel = dc.y >> 8;                                                  \
    if (rel != curRel) {                                                        \
      curRel = rel;                                                             \
      const unsigned short* Wr = Wt + (size_t)rel * OUT * HDIM;                 \
      _Pragma("unroll") for (int ks = 0; ks < 4; ks++)                          \
          _Pragma("unroll") for (int nt = 0; nt < NT; nt++)                     \
              wf[ks][nt] = *(const bf16x8*)(Wr +                                \
                  (size_t)(colBase + nt * 16 + l16) * HDIM + ks * 32 + quad * 8); \
    }                                                                           \
    int2 dN = (ci + 1 < nCh) ? descS[ci + 1] : make_int2(0, 0);                 \
    int2 dN2 = (ci + 2 < nCh) ? descS[ci + 2] : make_int2(0, 0);                \
    const int n1 = dN.y & 0xFF;                                                 \
    const int n2 = dN2.y & 0xFF;                                                \
    if (r0 < n2) oE0 = ebuf[dN2.x + r0];                                        \
    if (8 + r0 < n2) oE1 = ebuf[dN2.x + 8 + r0];                                \
    if (16 + r0 < n2) oE2 = ebuf[dN2.x + 16 + r0];                              \
    if (24 + r0 < n2) oE3 = ebuf[dN2.x + 24 + r0];                              \
    uint4 g0, g1, g2, g3;                                                       \
    if (r0 < n1) g0 = *(const uint4*)(Xb + (size_t)(iE0.x & 0xFFFFFu) * HDIM + k8 * 8); \
    if (8 + r0 < n1) g1 = *(const uint4*)(Xb + (size_t)(iE1.x & 0xFFFFFu) * HDIM + k8 * 8); \
    if (16 + r0 < n1) g2 = *(const uint4*)(Xb + (size_t)(iE2.x & 0xFFFFFu) * HDIM + k8 * 8); \
    if (24 + r0 < n1) g3 = *(const uint4*)(Xb + (size_t)(iE3.x & 0xFFFFFu) * HDIM + k8 * 8); \
    uint2 hN;                                                                   \
    if (isHandler && myCol < n1) hN = ebuf[dN.x + myCol];                       \
    f32x4 dacc[2][NT] = {};                                                     \
    _Pragma("unroll") for (int mt = 0; mt < 2; mt++) {                          \
      if (mt * 16 < nRows) {                                                    \
        __builtin_amdgcn_s_setprio(1);                                          \
        _Pragma("unroll") for (int ks = 0; ks < 4; ks++) {                      \
          bf16x8 a = *(const bf16x8*)&xs[CB][mt * 16 + l16][ks * 32 + quad * 8]; \
          _Pragma("unroll") for (int nt = 0; nt < NT; nt++)                     \
              dacc[mt][nt] = __builtin_amdgcn_mfma_f32_16x16x32_bf16(           \
                  a, wf[ks][nt], dacc[mt][nt], 0, 0, 0);                        \
        }                                                                       \
        __builtin_amdgcn_s_setprio(0);                                          \
      }                                                                         \
    }                                                                           \
    {                                                                           \
      bf16x8 bfv[NT];                                                           \
      _Pragma("unroll") for (int nt = 0; nt < NT; nt++) {                       \
        uint4 bw;                                                               \
        bw.x = cvtpk(dacc[0][nt][0], dacc[0][nt][1]);                           \
        bw.y = cvtpk(dacc[0][nt][2], dacc[0][nt][3]);                           \
        bw.z = cvtpk(dacc[1][nt][0], dacc[1][nt][1]);                           \
        bw.w = cvtpk(dacc[1][nt][2], dacc[1][nt][3]);                           \
        bfv[nt] = *(bf16x8*)&bw;                                                \
      }                                                                         \
      __builtin_amdgcn_s_setprio(1);                                            \
      _Pragma("unroll") for (int mt = 0; mt < MT_P; mt++) {                     \
        bf16x8 a = *(const bf16x8*)&pmat[CB][mt * 16 + l16][quad * 8];          \
        _Pragma("unroll") for (int nt = 0; nt < NT; nt++)                       \
            pacc[mt][nt] = __builtin_amdgcn_mfma_f32_16x16x32_bf16(             \
                a, bfv[nt], pacc[mt][nt], 0, 0, 0);                             \
      }                                                                         \
      __builtin_amdgcn_s_setprio(0);                                            \
    }                                                                           \
    if (r0 < n1) *(uint4*)&xs[CB ^ 1][r0][k8 * 8] = g0;                         \
    if (8 + r0 < n1) *(uint4*)&xs[CB ^ 1][8 + r0][k8 * 8] = g1;                 \
    if (16 + r0 < n1) *(uint4*)&xs[CB ^ 1][16 + r0][k8 * 8] = g2;               \
    if (24 + r0 < n1) *(uint4*)&xs[CB ^ 1][24 + r0][k8 * 8] = g3;               \
    if (isHandler) {                                                            \
      if (PDW >= 0) pmat[CB ^ 1][PDW][hslot] = 0;                               \
      if (myCol < n1) {                                                         \
        int dl = (int)(hN.x >> 20) & 127;                                       \
        pmat[CB ^ 1][dl][hslot] = f2bf(__uint_as_float(hN.y));                  \
        PDW = dl;                                                               \
      } else {                                                                  \
        PDW = -1;                                                               \
      }                                                                         \
    }                                                                           \
    if (ci + 1 < nCh) barrier_nodrain();                                        \
    ci++;                                                                       \
  }

// One block (128 threads, 2 waves) owns DSTBLK nodes; wave w owns columns
// [w*OUT/2, +OUT/2). Staging: thread covers rows r0+{0,8,16,24}, piece k8.
template <int OUT, bool BF16_RELU_OUT>
__launch_bounds__(128, 2)
__global__ void rgcn_layer(const unsigned short* __restrict__ Xb,  // [N][128] bf16
                           const unsigned short* __restrict__ Wt,  // [R][OUT][128] bf16
                           const uint2* __restrict__ ebuf,
                           const int* __restrict__ offsets, const int* __restrict__ counts,
                           const float* __restrict__ bias, void* __restrict__ Hout,
                           int nNodes) {
  constexpr int NT = OUT / 32;  // cols-per-wave/16: 4 (OUT=128) or 2 (OUT=64)
  __shared__ __align__(16) unsigned short xs[2][CHUNK][136];  // gathered src rows
  __shared__ __align__(16) unsigned short pmat[2][80][40];    // P[dloc][slot] = bf16(norm)
  __shared__ __align__(8) int2 descS[MAXCH];                  // {base, nRows|rel<<8}
  __shared__ int sBase[16], sCnt[16], sStart[17];

  const int t = threadIdx.x;
  const int w = t >> 6;
  const int lane = t & 63;
  const int quad = lane >> 4;
  const int l16 = lane & 15;
  const int r0 = t >> 4;     // gather base row 0..7 (covers r0, r0+8, +16, +24)
  const int k8 = t & 15;     // gather 8-elem column piece
  const bool isHandler = (t & 3) == 0;
  const int myCol = t >> 2;  // handler-owned edge index (0..31, fixed)
  // pmat column slot for edge myCol: eps^-1(e) = q*8 + m*4 + r
  const int hslot = ((myCol >> 2) & 3) * 8 + ((myCol >> 4) & 1) * 4 + (myCol & 3);
  const int nodeBase = blockIdx.x * DSTBLK;
  const int binBase = blockIdx.x * RELS;
  const int colBase = w * (OUT / 2);

  // one-time zero (stale LDS may hold NaN bit patterns; 0 * NaN = NaN)
  for (int i = t; i < 2 * CHUNK * 136 / 8; i += 128) ((uint4*)xs)[i] = make_uint4(0, 0, 0, 0);
  for (int i = t; i < 2 * 80 * 40 / 8; i += 128) ((uint4*)pmat)[i] = make_uint4(0, 0, 0, 0);

  // build chunk descriptor list (bins in relation order -> few W reloads)
  if (t < 16) {
    sBase[t] = offsets[binBase + t];
    sCnt[t] = counts[binBase + t];
  }
  __syncthreads();  // covers zero-init + sBase/sCnt (nothing in flight yet)
  if (t == 0) {
    int run = 0;
#pragma unroll
    for (int b = 0; b < 16; b++) {
      sStart[b] = run;
      run += (sCnt[b] + CHUNK - 1) / CHUNK;
    }
    sStart[16] = min(run, MAXCH);
  }
  __syncthreads();
  if (t < 16) {
    int st = sStart[t], ba = sBase[t], c = sCnt[t];
    for (int j = 0; j * CHUNK < c; j++)
      if (st + j < MAXCH)
        descS[st + j] = make_int2(ba + j * CHUNK, min(CHUNK, c - j * CHUNK) | (t << 8));
  }
  __syncthreads();
  const int nCh = sStart[16];

  f32x4 pacc[MT_P][NT] = {};  // persistent dst accumulator

  // ping/pong entry registers (plain named locals; nothing demotable)
  uint2 qE0, qE1, qE2, qE3, pE0, pE1, pE2, pE3;
  int pd0 = -1, pd1 = -1;  // handler prev-entry tracker per pmat buffer

  // prologue: stage chunk 0 into xs[0]/pmat[0]; prime qE = entries(chunk 1)
  if (nCh > 0) {
    int2 d0 = descS[0];
    int2 d1 = (nCh > 1) ? descS[1] : make_int2(0, 0);
    const int rows0 = d0.y & 0xFF;
    const int n1p = d1.y & 0xFF;
    uint2 a0, a1, a2, a3, am;
    if (r0 < rows0) a0 = ebuf[d0.x + r0];
    if (8 + r0 < rows0) a1 = ebuf[d0.x + 8 + r0];
    if (16 + r0 < rows0) a2 = ebuf[d0.x + 16 + r0];
    if (24 + r0 < rows0) a3 = ebuf[d0.x + 24 + r0];
    if (isHandler && myCol < rows0) am = ebuf[d0.x + myCol];
    if (r0 < n1p) qE0 = ebuf[d1.x + r0];
    if (8 + r0 < n1p) qE1 = ebuf[d1.x + 8 + r0];
    if (16 + r0 < n1p) qE2 = ebuf[d1.x + 16 + r0];
    if (24 + r0 < n1p) qE3 = ebuf[d1.x + 24 + r0];
    // gather + stage chunk 0 (full latency exposed once per block)
    if (r0 < rows0)
      *(uint4*)&xs[0][r0][k8 * 8] =
          *(const uint4*)(Xb + (size_t)(a0.x & 0xFFFFFu) * HDIM + k8 * 8);
    if (8 + r0 < rows0)
      *(uint4*)&xs[0][8 + r0][k8 * 8] =
          *(const uint4*)(Xb + (size_t)(a1.x & 0xFFFFFu) * HDIM + k8 * 8);
    if (16 + r0 < rows0)
      *(uint4*)&xs[0][16 + r0][k8 * 8] =
          *(const uint4*)(Xb + (size_t)(a2.x & 0xFFFFFu) * HDIM + k8 * 8);
    if (24 + r0 < rows0)
      *(uint4*)&xs[0][24 + r0][k8 * 8] =
          *(const uint4*)(Xb + (size_t)(a3.x & 0xFFFFFu) * HDIM + k8 * 8);
    if (isHandler && myCol < rows0) {
      int dl = (int)(am.x >> 20) & 127;
      pmat[0][dl][hslot] = f2bf(__uint_as_float(am.y));
      pd0 = dl;
    }
  }
  barrier_nodrain();  // qE prefetches stay in flight

  int curRel = -1;
  bf16x8 wf[4][NT];

  // 2x-unrolled driver: even phases read qE write pE; odd phases reverse.
  int ci = 0;
  while (ci < nCh) {
    PHASE(0, qE0, qE1, qE2, qE3, pE0, pE1, pE2, pE3, pd1)
    if (ci >= nCh) break;
    PHASE(1, pE0, pE1, pE2, pE3, qE0, qE1, qE2, qE3, pd0)
  }

  // epilogue: each (node, col) owned by exactly one lane -> plain stores
#pragma unroll
  for (int mt = 0; mt < MT_P; mt++) {
#pragma unroll
    for (int reg = 0; reg < 4; reg++) {
      int ld = mt * 16 + quad * 4 + reg;
      int node = nodeBase + ld;
      if (ld < DSTBLK && node < nNodes) {
#pragma unroll
        for (int nt = 0; nt < NT; nt++) {
          int col = colBase + nt * 16 + l16;
          float v = pacc[mt][nt][reg] + bias[col];
          if constexpr (BF16_RELU_OUT)
            ((unsigned short*)Hout)[(size_t)node * OUT + col] = f2bf(fmaxf(v, 0.f));
          else
            ((float*)Hout)[(size_t)node * OUT + col] = v;
        }
      }
    }
  }
}

extern "C" void kernel_launch(void* const* d_in, const int* in_sizes, int n_in,
                              void* d_out, int out_size, void* d_ws, size_t ws_size,
                              hipStream_t stream) {
  const int*   src   = (const int*)d_in[1];
  const int*   dst   = (const int*)d_in[2];
  const int*   etype = (const int*)d_in[3];
  const float* norm  = (const float*)d_in[4];
  const float* emb   = (const float*)d_in[5];
  const float* V1    = (const float*)d_in[6];
  const float* comp1 = (const float*)d_in[7];
  const float* bias1 = (const float*)d_in[8];
  const float* V2    = (const float*)d_in[9];
  const float* comp2 = (const float*)d_in[10];
  const float* bias2 = (const float*)d_in[11];
  float* out = (float*)d_out;

  const int N = in_sizes[0];  // 50000
  const int E = in_sizes[1];  // 1000000
  const int H = 128, O = 64;
  const int NB = (N + DSTBLK - 1) / DSTBLK;  // 758
  const int NBINS = NB * RELS;               // 12128
  const int EPAD_MAX = E + NBINS * 16;

  char* ws = (char*)d_ws;
  size_t off = 0;
  auto alloc = [&](size_t bytes) -> void* {
    void* p = ws + off;
    off += (bytes + 255) & ~(size_t)255;
    return p;
  };
  unsigned short* W1t  = (unsigned short*)alloc(sizeof(short) * RELS * H * H);
  unsigned short* W2t  = (unsigned short*)alloc(sizeof(short) * RELS * O * H);
  unsigned short* embh = (unsigned short*)alloc(sizeof(short) * (size_t)N * H);
  unsigned short* h1b  = (unsigned short*)alloc(sizeof(short) * (size_t)N * H);
  uint2* ebuf = (uint2*)alloc(sizeof(uint2) * EPAD_MAX);
  int* counts  = (int*)alloc(sizeof(int) * NBINS);
  int* cursor  = (int*)alloc(sizeof(int) * NBINS);
  int* offsets = (int*)alloc(sizeof(int) * (NBINS + 1));

  hipMemsetAsync(counts, 0, sizeof(int) * NBINS, stream);
  hipMemsetAsync(cursor, 0, sizeof(int) * NBINS, stream);

  cvt_bf16<<<((size_t)N * H / 8 + 255) / 256, 256, 0, stream>>>(emb, embh, N * H / 8);
  compute_w<<<(RELS * H * H + 255) / 256, 256, 0, stream>>>(comp1, V1, W1t, H);
  compute_w<<<(RELS * O * H + 255) / 256, 256, 0, stream>>>(comp2, V2, W2t, O);
  hist_bins<<<256, 256, 0, stream>>>(dst, etype, E, NBINS, counts);
  scan_offsets<<<1, 256, 0, stream>>>(counts, offsets, NBINS);
  scatter_bins<<<1024, 256, 0, stream>>>(src, dst, etype, norm, E, offsets, cursor, ebuf);

  rgcn_layer<128, true><<<NB, 128, 0, stream>>>(embh, W1t, ebuf, offsets, counts, bias1, (void*)h1b, N);
  rgcn_layer<64, false><<<NB, 128, 0, stream>>>(h1b, W2t, ebuf, offsets, counts, bias2, (void*)out, N);
}